// Round 2
// baseline (185.992 us; speedup 1.0000x reference)
//
#include <hip/hip_runtime.h>

constexpr int   NUM_CLASSES  = 10;
constexpr float LAMBDA_COORD = 5.0f;
constexpr float LAMBDA_NOOBJ = 0.5f;
constexpr int   BLOCK = 256;
// ntiles = 5,191,680/256 = 20,280 = 2028 blocks * 10 tiles exactly
constexpr int   NBLOCKS_MAX = 2028;

constexpr int LDSP_F  = 256 * 4;            // 1024 floats (pred tile)
constexpr int LDST_F  = 12 + 1024 + 16;     // pre-halo 12 + tile + post-halo 16
constexpr int LDST_FP = 1056;               // padded so buf[1] stays 16B-aligned

#define GLOAD_LDS16(gp, lp) \
    __builtin_amdgcn_global_load_lds( \
        (const __attribute__((address_space(1))) void*)(gp), \
        (__attribute__((address_space(3))) void*)(lp), 16, 0, 0)

// Identical math sequence to the previous (verified) kernel -> bit-exact.
__device__ __forceinline__ void slot(const float4 p, const float4 t,
                                     const float t4a, const float t4b,
                                     unsigned j0,
                                     float& coord, float& conf, float& cls)
{
    const float pm[4] = {p.x, p.y, p.z, p.w};
    const float tm[4] = {t.x, t.y, t.z, t.w};

#pragma unroll
    for (int m = 0; m < 4; ++m) {
        unsigned j  = j0 + (unsigned)m;
        float d     = pm[m] - tm[m];
        float sq    = d * d;
        float t4    = (j >= 15u) ? t4b : t4a;
        float sqo   = (t4 > 0.f) ? sq : 0.f;
        coord += ((j - 4u) >= 11u) ? sqo : 0.f;
        cls   += ((j - 5u) <  10u) ? sqo : 0.f;
    }

    bool  hasConf = (j0 - 1u) < 4u;            // j0 in [1,4]
    float pc = (j0 == 4u) ? pm[0]
             : (j0 == 3u) ? pm[1]
             : (j0 == 2u) ? pm[2]
             :              pm[3];
    float e   = __expf(-pc);
    float sig = 1.f / (1.f + e);
    bool  obj = t4a > 0.f;
    float dsv = sig - t4a;
    float confv = obj ? dsv * dsv : LAMBDA_NOOBJ * sig * sig;
    conf += hasConf ? confv : 0.f;
}

__global__ __launch_bounds__(BLOCK) void yolo_main(
    const float4* __restrict__ pred4,
    const float4* __restrict__ tgt4,
    const float*  __restrict__ tgt,
    float* __restrict__ ws,
    unsigned n4, unsigned nblocks)
{
    __shared__ float ldsP[2][LDSP_F];
    __shared__ float ldsT[2][LDST_FP];

    const int tid = (int)threadIdx.x;
    const unsigned ntiles = n4 / 256u;

    float coord = 0.f, conf = 0.f, cls = 0.f;

    // tiles for this block: T*nblocks + blockIdx.x  (grid-stride by tile ->
    // each thread sees EXACTLY the same slot sequence as the previous kernel)
    unsigned NT = (ntiles > blockIdx.x) ? ((ntiles - 1u - blockIdx.x) / nblocks + 1u) : 0u;

    if (NT > 0) {
        // ---- prologue: stage tile T=0 into buf 0 ----
        {
            unsigned s0 = blockIdx.x * 256u;
            GLOAD_LDS16(pred4 + s0 + tid, &ldsP[0][4 * tid]);
            GLOAD_LDS16(tgt4  + s0 + tid, &ldsT[0][12 + 4 * tid]);
            if (tid < 7) {
                int hs = (tid < 3) ? (int)s0 - 3 + tid : (int)s0 + 253 + tid;
                hs = hs < 0 ? 0 : hs;
                hs = hs > (int)n4 - 1 ? (int)n4 - 1 : hs;
                float4 hv = tgt4[hs];
                int off = (tid < 3) ? 4 * tid : 1036 + 4 * (tid - 3);
                *(float4*)&ldsT[0][off] = hv;
            }
        }
        __syncthreads();

        for (unsigned T = 0; T < NT; ++T) {
            const int cur  = (int)(T & 1u);
            const bool more = (T + 1u < NT);

            // ---- stage tile T+1 into buf cur^1 (issue-early) ----
            float4 hv = make_float4(0.f, 0.f, 0.f, 0.f);
            if (more) {
                unsigned s0n = (blockIdx.x + (T + 1u) * nblocks) * 256u;
                GLOAD_LDS16(pred4 + s0n + tid, &ldsP[cur ^ 1][4 * tid]);
                GLOAD_LDS16(tgt4  + s0n + tid, &ldsT[cur ^ 1][12 + 4 * tid]);
                if (tid < 7) {
                    int hs = (tid < 3) ? (int)s0n - 3 + tid : (int)s0n + 253 + tid;
                    hs = hs < 0 ? 0 : hs;
                    hs = hs > (int)n4 - 1 ? (int)n4 - 1 : hs;
                    hv = tgt4[hs];
                }
            }

            // ---- compute tile T from buf cur (all reads from LDS) ----
            {
                unsigned s0   = (blockIdx.x + T * nblocks) * 256u;
                float4 p = *(const float4*)&ldsP[cur][4 * tid];
                float4 t = *(const float4*)&ldsT[cur][12 + 4 * tid];
                unsigned base = (s0 + (unsigned)tid) * 4u;
                unsigned j0   = base % 15u;           // magic-mul
                int qoff = 4 * tid + 16 - (int)j0;    // LDS idx of tgt[15*cell0+4]
                float t4a = ldsT[cur][qoff];
                float t4b = ldsT[cur][qoff + ((j0 >= 12u) ? 15 : 0)];
                slot(p, t, t4a, t4b, j0, coord, conf, cls);
            }

            // ---- halo write-late (latency hidden under compute) ----
            if (more && tid < 7) {
                int off = (tid < 3) ? 4 * tid : 1036 + 4 * (tid - 3);
                *(float4*)&ldsT[cur ^ 1][off] = hv;
            }
            __syncthreads();   // drains gload_lds (vmcnt) + halo write (lgkm)
        }
    }

    // ---- ragged remainder (n4 % 256 != 0) — unused for this shape ----
    if (blockIdx.x == 0) {
        for (unsigned k = ntiles * 256u + (unsigned)tid; k < n4; k += BLOCK) {
            float4 p = pred4[k];
            float4 t = tgt4[k];
            unsigned base  = 4u * k;
            unsigned cell0 = base / 15u;
            unsigned c15   = cell0 * 15u;
            unsigned j0    = base - c15;
            float ta = tgt[c15 + 4u];
            float tb = tgt[(j0 >= 12u) ? c15 + 19u : c15 + 4u];
            slot(p, t, ta, tb, j0, coord, conf, cls);
        }
    }

    // wave64 shuffle reduce
#pragma unroll
    for (int off = 32; off > 0; off >>= 1) {
        coord += __shfl_down(coord, off);
        conf  += __shfl_down(conf,  off);
        cls   += __shfl_down(cls,   off);
    }

    __shared__ float s[3][4];
    int wave = tid >> 6, lane = tid & 63;
    if (lane == 0) { s[0][wave] = coord; s[1][wave] = conf; s[2][wave] = cls; }
    __syncthreads();

    if (tid == 0) {
        float c0 = s[0][0] + s[0][1] + s[0][2] + s[0][3];
        float c1 = s[1][0] + s[1][1] + s[1][2] + s[1][3];
        float c2 = s[2][0] + s[2][1] + s[2][2] + s[2][3];
        ws[blockIdx.x]               = c0;
        ws[nblocks + blockIdx.x]     = c1;
        ws[2 * nblocks + blockIdx.x] = c2;
    }
}

__global__ __launch_bounds__(BLOCK) void yolo_finalize(
    const float* __restrict__ ws, float* __restrict__ out, unsigned nblocks)
{
    float c0 = 0.f, c1 = 0.f, c2 = 0.f;
    for (unsigned i = threadIdx.x; i < nblocks; i += BLOCK) {
        c0 += ws[i];
        c1 += ws[nblocks + i];
        c2 += ws[2 * nblocks + i];
    }
#pragma unroll
    for (int off = 32; off > 0; off >>= 1) {
        c0 += __shfl_down(c0, off);
        c1 += __shfl_down(c1, off);
        c2 += __shfl_down(c2, off);
    }
    __shared__ float s[3][4];
    int wave = threadIdx.x >> 6, lane = threadIdx.x & 63;
    if (lane == 0) { s[0][wave] = c0; s[1][wave] = c1; s[2][wave] = c2; }
    __syncthreads();
    if (threadIdx.x == 0) {
        float coord = LAMBDA_COORD * (s[0][0] + s[0][1] + s[0][2] + s[0][3]);
        float conf  =                 s[1][0] + s[1][1] + s[1][2] + s[1][3];
        float cls   = (1.f / NUM_CLASSES) * (s[2][0] + s[2][1] + s[2][2] + s[2][3]);
        out[0] = coord + conf + cls;
        out[1] = coord;
        out[2] = conf;
        out[3] = cls;
    }
}

extern "C" void kernel_launch(void* const* d_in, const int* in_sizes, int n_in,
                              void* d_out, int out_size, void* d_ws, size_t ws_size,
                              hipStream_t stream) {
    const float* pred = (const float*)d_in[0];
    const float* tgt  = (const float*)d_in[1];
    float* out = (float*)d_out;
    float* ws  = (float*)d_ws;

    unsigned total = (unsigned)in_sizes[0];   // B*S*S*15 = 20,766,720 (div by 4)
    unsigned n4    = total / 4u;

    unsigned nblocks = NBLOCKS_MAX;
    size_t need = (size_t)nblocks * 3 * sizeof(float);
    if (need > ws_size) nblocks = (unsigned)(ws_size / (3 * sizeof(float)));

    yolo_main<<<nblocks, BLOCK, 0, stream>>>(
        (const float4*)pred, (const float4*)tgt, tgt, ws, n4, nblocks);
    yolo_finalize<<<1, BLOCK, 0, stream>>>(ws, out, nblocks);
}

// Round 3
// 179.497 us; speedup vs baseline: 1.0362x; 1.0362x over previous
//
#include <hip/hip_runtime.h>

typedef float f4v __attribute__((ext_vector_type(4)));

constexpr int   NUM_CLASSES  = 10;
constexpr float LAMBDA_COORD = 5.0f;
constexpr float LAMBDA_NOOBJ = 0.5f;
constexpr int   BLOCK = 256;
// 5,191,680 float4 slots = 2028 blocks * 256 threads * 10 tiles exactly
constexpr int   NBLOCKS_MAX = 2028;
constexpr int   LDST_W = 288;   // floats per wave-buffer: 12 pre + 256 + 16 post + pad

#define GLOAD_LDS16(gp, lp) \
    __builtin_amdgcn_global_load_lds( \
        (const __attribute__((address_space(1))) void*)(gp), \
        (__attribute__((address_space(3))) void*)(lp), 16, 0, 0)
#define WAITVM(n)  asm volatile("s_waitcnt vmcnt(" #n ")" ::: "memory")
#define WAITLGKM() asm volatile("s_waitcnt lgkmcnt(0)" ::: "memory")
#define SB()       __builtin_amdgcn_sched_barrier(0)

// Identical math sequence to the verified kernels -> bit-exact partials.
__device__ __forceinline__ void slot(const f4v p, const f4v t,
                                     const float t4a, const float t4b,
                                     unsigned j0,
                                     float& coord, float& conf, float& cls)
{
#pragma unroll
    for (int m = 0; m < 4; ++m) {
        unsigned j  = j0 + (unsigned)m;
        float d     = p[m] - t[m];
        float sq    = d * d;
        float t4    = (j >= 15u) ? t4b : t4a;
        float sqo   = (t4 > 0.f) ? sq : 0.f;
        coord += ((j - 4u) >= 11u) ? sqo : 0.f;
        cls   += ((j - 5u) <  10u) ? sqo : 0.f;
    }
    bool  hasConf = (j0 - 1u) < 4u;            // j0 in [1,4]
    float pc = (j0 == 4u) ? p[0]
             : (j0 == 3u) ? p[1]
             : (j0 == 2u) ? p[2]
             :              p[3];
    float e   = __expf(-pc);
    float sig = 1.f / (1.f + e);
    bool  obj = t4a > 0.f;
    float dsv = sig - t4a;
    float confv = obj ? dsv * dsv : LAMBDA_NOOBJ * sig * sig;
    conf += hasConf ? confv : 0.f;
}

// Stage tile TT of this wave: pred -> reg (non-temporal), tgt -> LDS (async DMA),
// halo (12 pre + 16 post floats) -> reg. Exactly 3 wave-level VMEM ops.
#define STAGE(LBUF, TT, PREG, HREG) do {                                     \
    unsigned kk_ = idx + (unsigned)(TT) * S;                                 \
    PREG = __builtin_nontemporal_load((const f4v*)pred4 + kk_);              \
    GLOAD_LDS16((const f4v*)tgt4 + kk_, (LBUF) + 12 + 4 * lane);             \
    if (lane < 7u) {                                                         \
        int kw_ = (int)(kk_ - lane);                                         \
        int hs_ = (lane < 3u) ? kw_ - 3 + (int)lane : kw_ + 61 + (int)lane;  \
        hs_ = hs_ < 0 ? 0 : hs_;                                             \
        hs_ = hs_ > (int)n4 - 1 ? (int)n4 - 1 : hs_;                         \
        HREG = *((const f4v*)tgt4 + hs_);                                    \
    }                                                                        \
} while (0)

// Halo reg->LDS write, then all LDS reads for tile TT of this wave.
#define CLOAD(LBUF, TT, HREG, TV, AV, BV, JV) do {                           \
    if (lane < 7u) {                                                         \
        int off_ = (lane < 3u) ? 4 * (int)lane : 268 + 4 * ((int)lane - 3);  \
        *(f4v*)((LBUF) + off_) = HREG;                                       \
    }                                                                        \
    unsigned kk_ = idx + (unsigned)(TT) * S;                                 \
    JV = (4u * kk_) % 15u;                                                   \
    int q_ = 4 * (int)lane + 16 - (int)JV;                                   \
    TV = *(const f4v*)((LBUF) + 12 + 4 * lane);                              \
    AV = (LBUF)[q_];                                                         \
    BV = (LBUF)[q_ + ((JV >= 12u) ? 15 : 0)];                                \
} while (0)

__global__ __launch_bounds__(BLOCK) void yolo_main(
    const float* __restrict__ pred4,
    const float* __restrict__ tgt4,
    float* __restrict__ ws,
    unsigned n4, unsigned nblocks)
{
    __shared__ float ldsT[4][2][LDST_W];   // per-wave double buffers, 9.2 KB

    const unsigned tid  = threadIdx.x;
    const unsigned lane = tid & 63u;
    const unsigned wv   = tid >> 6;
    const unsigned S    = nblocks * 256u;
    const unsigned idx  = blockIdx.x * 256u + tid;
    const unsigned NTu  = n4 / S;          // uniform tiles per thread (10)

    float* L0 = &ldsT[wv][0][0];
    float* L1 = &ldsT[wv][1][0];

    float coord = 0.f, conf = 0.f, cls = 0.f;
    f4v pA = {0,0,0,0}, pB = {0,0,0,0}, hA = {0,0,0,0}, hB = {0,0,0,0};

    if (NTu >= 2u) {
        STAGE(L0, 0, pA, hA); SB();
        STAGE(L1, 1, pB, hB); SB();
        unsigned T = 0;
        for (; T + 1u < NTu; T += 2u) {
            // ---- tile T (buf L0) ----
            WAITVM(3); SB();                       // T's 3 ops done, T+1's in flight
            f4v tA; float aA, bA; unsigned jA;
            CLOAD(L0, T, hA, tA, aA, bA, jA);
            WAITLGKM(); SB();                      // LDS reads in regs before re-stage
            f4v puA = pA;
            if (T + 2u < NTu) { STAGE(L0, T + 2u, pA, hA); }
            SB();
            slot(puA, tA, aA, bA, jA, coord, conf, cls);   // math hides DMA

            // ---- tile T+1 (buf L1) ----
            if (T + 2u < NTu) { WAITVM(3); } else { WAITVM(0); }
            SB();
            f4v tB; float aB, bB; unsigned jB;
            CLOAD(L1, T + 1u, hB, tB, aB, bB, jB);
            WAITLGKM(); SB();
            f4v puB = pB;
            if (T + 3u < NTu) { STAGE(L1, T + 3u, pB, hB); }
            SB();
            slot(puB, tB, aB, bB, jB, coord, conf, cls);
        }
        if (T < NTu) {                             // odd NTu: leftover in L0
            WAITVM(0); SB();
            f4v tA; float aA, bA; unsigned jA;
            CLOAD(L0, T, hA, tA, aA, bA, jA);
            WAITLGKM(); SB();
            slot(pA, tA, aA, bA, jA, coord, conf, cls);
        }
    } else if (NTu == 1u) {
        STAGE(L0, 0, pA, hA); SB();
        WAITVM(0); SB();
        f4v tA; float aA, bA; unsigned jA;
        CLOAD(L0, 0, hA, tA, aA, bA, jA);
        WAITLGKM(); SB();
        slot(pA, tA, aA, bA, jA, coord, conf, cls);
    }

    // ragged remainder (n4 % S != 0) — empty for the graded shape
    for (unsigned k = NTu * S + idx; k < n4; k += S) {
        f4v p = *((const f4v*)pred4 + k);
        f4v t = *((const f4v*)tgt4 + k);
        unsigned base  = 4u * k;
        unsigned cell0 = base / 15u;
        unsigned c15   = cell0 * 15u;
        unsigned j0    = base - c15;
        float ta = tgt4[c15 + 4u];
        float tb = tgt4[(j0 >= 12u) ? c15 + 19u : c15 + 4u];
        slot(p, t, ta, tb, j0, coord, conf, cls);
    }

    // wave64 shuffle reduce (unchanged topology -> bit-identical)
#pragma unroll
    for (int off = 32; off > 0; off >>= 1) {
        coord += __shfl_down(coord, off);
        conf  += __shfl_down(conf,  off);
        cls   += __shfl_down(cls,   off);
    }

    __shared__ float s[3][4];
    if (lane == 0) { s[0][wv] = coord; s[1][wv] = conf; s[2][wv] = cls; }
    __syncthreads();

    if (tid == 0) {
        float c0 = s[0][0] + s[0][1] + s[0][2] + s[0][3];
        float c1 = s[1][0] + s[1][1] + s[1][2] + s[1][3];
        float c2 = s[2][0] + s[2][1] + s[2][2] + s[2][3];
        ws[blockIdx.x]               = c0;
        ws[nblocks + blockIdx.x]     = c1;
        ws[2 * nblocks + blockIdx.x] = c2;
    }
}

__global__ __launch_bounds__(BLOCK) void yolo_finalize(
    const float* __restrict__ ws, float* __restrict__ out, unsigned nblocks)
{
    float c0 = 0.f, c1 = 0.f, c2 = 0.f;
    for (unsigned i = threadIdx.x; i < nblocks; i += BLOCK) {
        c0 += ws[i];
        c1 += ws[nblocks + i];
        c2 += ws[2 * nblocks + i];
    }
#pragma unroll
    for (int off = 32; off > 0; off >>= 1) {
        c0 += __shfl_down(c0, off);
        c1 += __shfl_down(c1, off);
        c2 += __shfl_down(c2, off);
    }
    __shared__ float s[3][4];
    int wave = threadIdx.x >> 6, lane = threadIdx.x & 63;
    if (lane == 0) { s[0][wave] = c0; s[1][wave] = c1; s[2][wave] = c2; }
    __syncthreads();
    if (threadIdx.x == 0) {
        float coord = LAMBDA_COORD * (s[0][0] + s[0][1] + s[0][2] + s[0][3]);
        float conf  =                 s[1][0] + s[1][1] + s[1][2] + s[1][3];
        float cls   = (1.f / NUM_CLASSES) * (s[2][0] + s[2][1] + s[2][2] + s[2][3]);
        out[0] = coord + conf + cls;
        out[1] = coord;
        out[2] = conf;
        out[3] = cls;
    }
}

extern "C" void kernel_launch(void* const* d_in, const int* in_sizes, int n_in,
                              void* d_out, int out_size, void* d_ws, size_t ws_size,
                              hipStream_t stream) {
    const float* pred = (const float*)d_in[0];
    const float* tgt  = (const float*)d_in[1];
    float* out = (float*)d_out;
    float* ws  = (float*)d_ws;

    unsigned total = (unsigned)in_sizes[0];   // B*S*S*15 = 20,766,720 (div by 4)
    unsigned n4    = total / 4u;

    unsigned nblocks = NBLOCKS_MAX;
    size_t need = (size_t)nblocks * 3 * sizeof(float);
    if (need > ws_size) nblocks = (unsigned)(ws_size / (3 * sizeof(float)));

    yolo_main<<<nblocks, BLOCK, 0, stream>>>(pred, tgt, ws, n4, nblocks);
    yolo_finalize<<<1, BLOCK, 0, stream>>>(ws, out, nblocks);
}